// Round 9
// baseline (127.986 us; speedup 1.0000x reference)
//
#include <hip/hip_runtime.h>
#include <math.h>

#define BN 1024
#define DN 256
#define HN 256
#define KN 8
#define SP 260  // padded row stride (floats) for per-row LDS vectors
#define PS ((size_t)BN * BN)       // plane payload (floats)
#define PSTRIDE (PS + 256)         // +1KB stagger: planes hit different HBM channel alignment
typedef unsigned long long u64;

// ---------------- Kernel A: pairwise squared-distance PARTIALS ----------------
// D-split for occupancy (R8, kept: measured k_dist2 ~58us -> ~5us). Block
// (bx,by,bz) computes the 64x64 tile's partial d^2 over d-chunk bz*64..+63.
// Grid (16,16,4) = 1024 blocks = 4 blocks/CU. LDS 32KB/block.
__global__ __launch_bounds__(256) void k_dist2(const float* __restrict__ x,
                                               float* __restrict__ part) {
  __shared__ float4 xi4[64][16];
  __shared__ float4 xj4[64][16];
  const int tid = threadIdx.x;
  const int tx = tid & 15, ty = tid >> 4;
  const int i0 = blockIdx.y << 6, j0 = blockIdx.x << 6;
  const int d0 = blockIdx.z << 6;

#pragma unroll
  for (int q = 0; q < 4; ++q) {
    int f = (q << 8) + tid;
    int row = f >> 4, s = f & 15;
    int p = s ^ (((row >> 2) & 7) ^ ((row & 3) << 1));
    xi4[row][p] = *reinterpret_cast<const float4*>(
        x + (size_t)(i0 + row) * DN + d0 + (s << 2));
    xj4[row][p] = *reinterpret_cast<const float4*>(
        x + (size_t)(j0 + row) * DN + d0 + (s << 2));
  }
  __syncthreads();

  float acc[4][4];
#pragma unroll
  for (int m = 0; m < 4; ++m)
#pragma unroll
    for (int n = 0; n < 4; ++n) acc[m][n] = 0.f;

  const int pia = ty & 7, pib = tx & 7;
#pragma unroll 4
  for (int g = 0; g < 16; ++g) {
    float4 A[4], Bv[4];
#pragma unroll
    for (int m = 0; m < 4; ++m) A[m] = xi4[(ty << 2) + m][g ^ pia ^ (m << 1)];
#pragma unroll
    for (int n = 0; n < 4; ++n) Bv[n] = xj4[(tx << 2) + n][g ^ pib ^ (n << 1)];
#pragma unroll
    for (int m = 0; m < 4; ++m)
#pragma unroll
      for (int n = 0; n < 4; ++n) {
        float t0 = A[m].x - Bv[n].x;
        float t1 = A[m].y - Bv[n].y;
        float t2 = A[m].z - Bv[n].z;
        float t3 = A[m].w - Bv[n].w;
        acc[m][n] = fmaf(t0, t0, acc[m][n]);
        acc[m][n] = fmaf(t1, t1, acc[m][n]);
        acc[m][n] = fmaf(t2, t2, acc[m][n]);
        acc[m][n] = fmaf(t3, t3, acc[m][n]);
      }
  }

  float* plane = part + (size_t)blockIdx.z * PSTRIDE;
#pragma unroll
  for (int m = 0; m < 4; ++m) {
    float4 o;
    o.x = acc[m][0]; o.y = acc[m][1]; o.z = acc[m][2]; o.w = acc[m][3];
    *reinterpret_cast<float4*>(plane + (size_t)(i0 + (ty << 2) + m) * BN +
                               j0 + (tx << 2)) = o;
  }
}

// ---------------- Kernel A2: plane reduction (streaming) ----------------
// dist2 = p0+p1+p2+p3 in fixed order (same numerics as the R8 in-phase sum,
// which passed at absmax 0.0156). 1024 blocks x 256 thr, one float4 each:
// 20MB coalesced at full MLP (~3-5us). Moved OUT of the 1-block/CU
// selection kernel where the 4-plane read was latency-naked (+58us, R8).
__global__ __launch_bounds__(256) void k_reduce(const float* __restrict__ part,
                                                float* __restrict__ dist2) {
  size_t i = (((size_t)blockIdx.x << 8) + threadIdx.x) << 2;
  float4 v0 = *reinterpret_cast<const float4*>(part + i);
  float4 v1 = *reinterpret_cast<const float4*>(part + PSTRIDE + i);
  float4 v2 = *reinterpret_cast<const float4*>(part + 2 * PSTRIDE + i);
  float4 v3 = *reinterpret_cast<const float4*>(part + 3 * PSTRIDE + i);
  float4 o;
  o.x = v0.x + v1.x + v2.x + v3.x;
  o.y = v0.y + v1.y + v2.y + v3.y;
  o.z = v0.z + v1.z + v2.z + v3.z;
  o.w = v0.w + v1.w + v2.w + v3.w;
  *reinterpret_cast<float4*>(dist2 + i) = o;
}

// ---------- Kernel B: fused top-K + epilogue (strip-dot matvecs) ----------
// Phase-1 reverted to the R7 single-plane read (4 coalesced loads/lane).
// Matvecs: coalesced strip-dot with butterfly reduce-scatter (R7).
__global__ __launch_bounds__(256) void k_sel_row(
    const float* __restrict__ x, const float* __restrict__ W_diff,
    const float* __restrict__ b_diff, const float* __restrict__ W_tau,
    const float* __restrict__ b_tau, const float* __restrict__ W_agg,
    const float* __restrict__ b_agg, const float* __restrict__ W_res,
    const float* __restrict__ b_res, const float* __restrict__ gamma,
    const float* __restrict__ beta, const float* __restrict__ dist2,
    float* __restrict__ out) {
  const int tid = threadIdx.x;
  const int lane = tid & 63, wv = tid >> 6;
  const int r0 = blockIdx.x << 2;
  __shared__ float s_x[4 * SP];
  __shared__ float s_s[4 * SP];
  __shared__ float s_hk[4 * SP];
  __shared__ float s_y[4 * SP];
  __shared__ float s_tau[4];
  __shared__ float s_mu[4], s_rs[4];
  __shared__ int s_idx[4 * KN];

#pragma unroll
  for (int r = 0; r < 4; ++r)
    s_x[r * SP + tid] = x[(size_t)(r0 + r) * DN + tid];

  // ---- phase 1: top-8 for row r0+wv (one wave per row, no barriers) ----
  {
    const int row = r0 + wv;
    const float* base = dist2 + (size_t)row * BN;
    u64 key[16];
#pragma unroll
    for (int q = 0; q < 4; ++q) {
      int j = (q << 8) + (lane << 2);
      float4 v = *reinterpret_cast<const float4*>(base + j);
      key[q * 4 + 0] = ((u64)__float_as_uint(v.x) << 32) | (unsigned)(j + 0);
      key[q * 4 + 1] = ((u64)__float_as_uint(v.y) << 32) | (unsigned)(j + 1);
      key[q * 4 + 2] = ((u64)__float_as_uint(v.z) << 32) | (unsigned)(j + 2);
      key[q * 4 + 3] = ((u64)__float_as_uint(v.w) << 32) | (unsigned)(j + 3);
    }
    for (int r = 0; r < KN; ++r) {
      u64 m = key[0];
#pragma unroll
      for (int l = 1; l < 16; ++l) m = key[l] < m ? key[l] : m;
#pragma unroll
      for (int off = 32; off > 0; off >>= 1) {
        u64 o = __shfl_xor(m, off);
        m = o < m ? o : m;
      }
      if (lane == 0) s_idx[wv * KN + r] = (int)(unsigned)(m & 0xffffffffull);
#pragma unroll
      for (int l = 0; l < 16; ++l)
        if (key[l] == m) key[l] = ~0ull;
    }
  }
  __syncthreads();  // s_idx + s_x visible

  // ---- |diff| sums over the K neighbors ----
#pragma unroll
  for (int r = 0; r < 4; ++r) {
    float xv = s_x[r * SP + tid];
    float s = 0.f;
#pragma unroll
    for (int k = 0; k < KN; ++k) {
      int j = s_idx[r * KN + k];
      s += fabsf(xv - x[(size_t)j * DN + tid]);
    }
    s_s[r * SP + tid] = s;
  }
  // ---- tau: wave wv reduces row wv ----
  {
    float p = 0.f;
#pragma unroll
    for (int q = 0; q < DN / 64; ++q) {
      int d = lane + (q << 6);
      p += s_x[wv * SP + d] * W_tau[d];
    }
#pragma unroll
    for (int off = 32; off > 0; off >>= 1) p += __shfl_down(p, off);
    if (lane == 0) {
      float z = p + b_tau[0];
      float sp = z > 0.f ? z + log1pf(expf(-z)) : log1pf(expf(z));
      s_tau[wv] = fmaxf(sp, 0.01f) + 1.0f;
    }
  }
  __syncthreads();  // covers s_s and s_tau

  // ---- matvec passes: coalesced strip-dot ----
  auto ldchunk = [&](float4* g, const float* W, int hb) {
#pragma unroll
    for (int j = 0; j < 8; ++j)
      g[j] = *reinterpret_cast<const float4*>(W + ((size_t)(hb + j) << 8) +
                                              (lane << 2));
  };
  auto dotchunk = [&](const float4* w, const float4* sv) -> float {
    float v32[32];
#pragma unroll
    for (int j = 0; j < 8; ++j)
#pragma unroll
      for (int r = 0; r < 4; ++r) {
        float a = w[j].x * sv[r].x;
        a = fmaf(w[j].y, sv[r].y, a);
        a = fmaf(w[j].z, sv[r].z, a);
        a = fmaf(w[j].w, sv[r].w, a);
        v32[j * 4 + r] = a;
      }
    float v16[16], v8[8], v4[4], v2[2], vf;
#pragma unroll
    for (int m = 0; m < 16; ++m) {
      float keep = (lane & 1) ? v32[2 * m + 1] : v32[2 * m];
      float send = (lane & 1) ? v32[2 * m] : v32[2 * m + 1];
      v16[m] = keep + __shfl_xor(send, 1);
    }
#pragma unroll
    for (int m = 0; m < 8; ++m) {
      float keep = (lane & 2) ? v16[2 * m + 1] : v16[2 * m];
      float send = (lane & 2) ? v16[2 * m] : v16[2 * m + 1];
      v8[m] = keep + __shfl_xor(send, 2);
    }
#pragma unroll
    for (int m = 0; m < 4; ++m) {
      float keep = (lane & 4) ? v8[2 * m + 1] : v8[2 * m];
      float send = (lane & 4) ? v8[2 * m] : v8[2 * m + 1];
      v4[m] = keep + __shfl_xor(send, 4);
    }
#pragma unroll
    for (int m = 0; m < 2; ++m) {
      float keep = (lane & 8) ? v4[2 * m + 1] : v4[2 * m];
      float send = (lane & 8) ? v4[2 * m] : v4[2 * m + 1];
      v2[m] = keep + __shfl_xor(send, 8);
    }
    {
      float keep = (lane & 16) ? v2[1] : v2[0];
      float send = (lane & 16) ? v2[0] : v2[1];
      vf = keep + __shfl_xor(send, 16);
    }
    vf += __shfl_xor(vf, 32);
    return vf;
  };

  const int oj = (lane & 31) >> 2;
  const int orr = lane & 3;

  // pass A: W_diff -> s_hk
  {
    float4 sA[4];
#pragma unroll
    for (int r = 0; r < 4; ++r)
      sA[r] = *reinterpret_cast<const float4*>(&s_s[r * SP + (lane << 2)]);
    float4 g[8];
    ldchunk(g, W_diff, wv << 6);
#pragma unroll
    for (int s = 0; s < 8; ++s) {
      float4 w[8];
#pragma unroll
      for (int j = 0; j < 8; ++j) w[j] = g[j];
      if (s < 7) ldchunk(g, W_diff, (wv << 6) + ((s + 1) << 3));
      float vf = dotchunk(w, sA);
      int h = (wv << 6) + (s << 3) + oj;
      s_hk[orr * SP + h] = (vf * 0.125f + b_diff[h]) / s_tau[orr];
    }
  }
  __syncthreads();

  // pass B: W_agg (on h_k) then W_res (on x); relu + residual -> s_y
  {
    float4 sH[4], sX[4];
#pragma unroll
    for (int r = 0; r < 4; ++r) {
      sH[r] = *reinterpret_cast<const float4*>(&s_hk[r * SP + (lane << 2)]);
      sX[r] = *reinterpret_cast<const float4*>(&s_x[r * SP + (lane << 2)]);
    }
    float aggv[8];
    float4 g[8];
    ldchunk(g, W_agg, wv << 6);
#pragma unroll
    for (int s = 0; s < 8; ++s) {
      float4 w[8];
#pragma unroll
      for (int j = 0; j < 8; ++j) w[j] = g[j];
      if (s < 7) ldchunk(g, W_agg, (wv << 6) + ((s + 1) << 3));
      aggv[s] = dotchunk(w, sH);
    }
    ldchunk(g, W_res, wv << 6);
#pragma unroll
    for (int s = 0; s < 8; ++s) {
      float4 w[8];
#pragma unroll
      for (int j = 0; j < 8; ++j) w[j] = g[j];
      if (s < 7) ldchunk(g, W_res, (wv << 6) + ((s + 1) << 3));
      float resv = dotchunk(w, sX);
      int h = (wv << 6) + (s << 3) + oj;
      float yv = fmaxf(aggv[s] + b_agg[h], 0.f) + resv + b_res[h];
      s_y[orr * SP + h] = yv;
    }
  }
  __syncthreads();

  // ---- LayerNorm: wave wv reduces row wv ----
  {
    float sum = 0.f, sq = 0.f;
#pragma unroll
    for (int q = 0; q < HN / 64; ++q) {
      float v = s_y[wv * SP + lane + (q << 6)];
      sum += v;
      sq += v * v;
    }
#pragma unroll
    for (int off = 32; off > 0; off >>= 1) {
      sum += __shfl_down(sum, off);
      sq += __shfl_down(sq, off);
    }
    if (lane == 0) {
      float mu = sum * (1.f / HN);
      float var = sq * (1.f / HN) - mu * mu;
      s_mu[wv] = mu;
      s_rs[wv] = 1.f / sqrtf(var + 1e-5f);
    }
  }
  __syncthreads();

  float g = gamma[tid], be = beta[tid];
#pragma unroll
  for (int r = 0; r < 4; ++r) {
    out[(size_t)(r0 + r) * HN + tid] =
        (s_y[r * SP + tid] - s_mu[r]) * s_rs[r] * g + be;
  }
}

extern "C" void kernel_launch(void* const* d_in, const int* in_sizes, int n_in,
                              void* d_out, int out_size, void* d_ws,
                              size_t ws_size, hipStream_t stream) {
  const float* x = (const float*)d_in[0];
  const float* W_diff = (const float*)d_in[1];
  const float* b_diff = (const float*)d_in[2];
  const float* W_tau = (const float*)d_in[3];
  const float* b_tau = (const float*)d_in[4];
  const float* W_agg = (const float*)d_in[5];
  const float* b_agg = (const float*)d_in[6];
  const float* W_res = (const float*)d_in[7];
  const float* b_res = (const float*)d_in[8];
  const float* gamma = (const float*)d_in[9];
  const float* beta = (const float*)d_in[10];
  float* out = (float*)d_out;

  float* part = (float*)d_ws;                  // 4 staggered planes
  float* dist2 = part + 4 * PSTRIDE;           // reduced plane (4 MB)

  dim3 gA(BN / 64, BN / 64, 4);
  k_dist2<<<gA, 256, 0, stream>>>(x, part);
  k_reduce<<<PS / (4 * 256), 256, 0, stream>>>(part, dist2);
  k_sel_row<<<BN / 4, 256, 0, stream>>>(x, W_diff, b_diff, W_tau, b_tau,
                                        W_agg, b_agg, W_res, b_res, gamma,
                                        beta, dist2, out);
}

// Round 10
// 110.661 us; speedup vs baseline: 1.1566x; 1.1566x over previous
//
#include <hip/hip_runtime.h>
#include <math.h>

#define BN 1024
#define DN 256
#define HN 256
#define KN 8
#define SP 260  // padded row stride (floats) for per-row LDS vectors
typedef unsigned long long u64;

// ---------------- Kernel A: pairwise squared distances ----------------
// R7 monolithic 64x64 tile (measured best overall), now 512 threads =
// 8 waves = 2 waves/SIMD (was 1): TLP hides LDS latency. Per-thread tile
// 2x4 (ty 0..31 owns rows 2ty..2ty+1). Per-(i,j) FMA order identical to
// R7 -> bit-identical dist2 -> identical top-k selection.
__global__ __launch_bounds__(512) void k_dist2(const float* __restrict__ x,
                                               float* __restrict__ dist2) {
  __shared__ float4 xi4[64][32];
  __shared__ float4 xj4[64][32];
  const int tid = threadIdx.x;
  const int tx = tid & 15, ty = tid >> 4;  // ty 0..31
  const int i0 = blockIdx.y << 6, j0 = blockIdx.x << 6;
  const int pim = (ty >> 1) & 7;  // rows 2ty,2ty+1 share row>>2 = ty>>1
  const int pjm = tx & 7;
  float acc[2][4];
#pragma unroll
  for (int m = 0; m < 2; ++m)
#pragma unroll
    for (int n = 0; n < 4; ++n) acc[m][n] = 0.f;

  float4 A0[2], B0[4], A1[2], B1[4];

  auto loadg = [&](float4* Ad, float4* Bd, int g) {
    const int pi = g ^ pim, pj = g ^ pjm;
#pragma unroll
    for (int m = 0; m < 2; ++m) Ad[m] = xi4[(ty << 1) + m][pi];
#pragma unroll
    for (int n = 0; n < 4; ++n) Bd[n] = xj4[(tx << 2) + n][pj];
  };
  auto comp = [&](const float4* Ad, const float4* Bd) {
#pragma unroll
    for (int m = 0; m < 2; ++m)
#pragma unroll
      for (int n = 0; n < 4; ++n) {
        float t0 = Ad[m].x - Bd[n].x;
        float t1 = Ad[m].y - Bd[n].y;
        float t2 = Ad[m].z - Bd[n].z;
        float t3 = Ad[m].w - Bd[n].w;
        acc[m][n] = fmaf(t0, t0, acc[m][n]);
        acc[m][n] = fmaf(t1, t1, acc[m][n]);
        acc[m][n] = fmaf(t2, t2, acc[m][n]);
        acc[m][n] = fmaf(t3, t3, acc[m][n]);
      }
  };

  for (int c = 0; c < 2; ++c) {
    __syncthreads();
#pragma unroll
    for (int q = 0; q < 4; ++q) {  // 4 x 512 = 2048 float4 slots
      int f = (q << 9) + tid;
      int row = f >> 5, s = f & 31;
      int p = s ^ ((row >> 2) & 7);
      xi4[row][p] = *reinterpret_cast<const float4*>(
          x + (size_t)(i0 + row) * DN + (c << 7) + (s << 2));
      xj4[row][p] = *reinterpret_cast<const float4*>(
          x + (size_t)(j0 + row) * DN + (c << 7) + (s << 2));
    }
    __syncthreads();

    loadg(A0, B0, 0);
    for (int g = 0; g < 32; g += 2) {
      loadg(A1, B1, g + 1);
      comp(A0, B0);
      loadg(A0, B0, (g + 2) & 31);  // wrap-load on last iter: discarded
      comp(A1, B1);
    }
  }
#pragma unroll
  for (int m = 0; m < 2; ++m) {
    float4 o;
    o.x = acc[m][0]; o.y = acc[m][1]; o.z = acc[m][2]; o.w = acc[m][3];
    *reinterpret_cast<float4*>(dist2 + (size_t)(i0 + (ty << 1) + m) * BN +
                               j0 + (tx << 2)) = o;
  }
}

// ---------- Kernel B: fused top-K + epilogue, 8 waves (2/SIMD) ----------
// R7 structure with 512 threads: matvec h-ranges split across 8 waves
// (wave w owns h in [32w, 32w+32), 4 chunks of 8; dotchunk unchanged ->
// bit-identical per-h results). Staging / |diff| / out split by thread
// half (half = tid>>8, t2 = tid&255). phase1 / tau / LN stay on waves 0-3
// (wave-granular branch, no internal barriers).
__global__ __launch_bounds__(512) void k_sel_row(
    const float* __restrict__ x, const float* __restrict__ W_diff,
    const float* __restrict__ b_diff, const float* __restrict__ W_tau,
    const float* __restrict__ b_tau, const float* __restrict__ W_agg,
    const float* __restrict__ b_agg, const float* __restrict__ W_res,
    const float* __restrict__ b_res, const float* __restrict__ gamma,
    const float* __restrict__ beta, const float* __restrict__ dist2,
    float* __restrict__ out) {
  const int tid = threadIdx.x;
  const int lane = tid & 63, wv = tid >> 6;  // wv 0..7
  const int half = tid >> 8, t2 = tid & 255;
  const int r0 = blockIdx.x << 2;
  __shared__ float s_x[4 * SP];
  __shared__ float s_s[4 * SP];
  __shared__ float s_hk[4 * SP];
  __shared__ float s_y[4 * SP];
  __shared__ float s_tau[4];
  __shared__ float s_mu[4], s_rs[4];
  __shared__ int s_idx[4 * KN];

  // stage x rows: 512 threads, 2 rows each half
#pragma unroll
  for (int r2 = 0; r2 < 2; ++r2) {
    int rr = (half << 1) + r2;
    s_x[rr * SP + t2] = x[(size_t)(r0 + rr) * DN + t2];
  }

  // ---- phase 1: top-8 for row r0+wv on waves 0-3 (no barriers inside) ----
  if (wv < 4) {
    const int row = r0 + wv;
    const float* base = dist2 + (size_t)row * BN;
    u64 key[16];
#pragma unroll
    for (int q = 0; q < 4; ++q) {
      int j = (q << 8) + (lane << 2);
      float4 v = *reinterpret_cast<const float4*>(base + j);
      key[q * 4 + 0] = ((u64)__float_as_uint(v.x) << 32) | (unsigned)(j + 0);
      key[q * 4 + 1] = ((u64)__float_as_uint(v.y) << 32) | (unsigned)(j + 1);
      key[q * 4 + 2] = ((u64)__float_as_uint(v.z) << 32) | (unsigned)(j + 2);
      key[q * 4 + 3] = ((u64)__float_as_uint(v.w) << 32) | (unsigned)(j + 3);
    }
    for (int r = 0; r < KN; ++r) {
      u64 m = key[0];
#pragma unroll
      for (int l = 1; l < 16; ++l) m = key[l] < m ? key[l] : m;
#pragma unroll
      for (int off = 32; off > 0; off >>= 1) {
        u64 o = __shfl_xor(m, off);
        m = o < m ? o : m;
      }
      if (lane == 0) s_idx[wv * KN + r] = (int)(unsigned)(m & 0xffffffffull);
#pragma unroll
      for (int l = 0; l < 16; ++l)
        if (key[l] == m) key[l] = ~0ull;
    }
  }
  __syncthreads();  // s_idx + s_x visible

  // ---- |diff| sums over the K neighbors: 2 rows per thread-half ----
#pragma unroll
  for (int r2 = 0; r2 < 2; ++r2) {
    int rr = (half << 1) + r2;
    float xv = s_x[rr * SP + t2];
    float s = 0.f;
#pragma unroll
    for (int k = 0; k < KN; ++k) {
      int j = s_idx[rr * KN + k];
      s += fabsf(xv - x[(size_t)j * DN + t2]);
    }
    s_s[rr * SP + t2] = s;
  }
  // ---- tau: waves 0-3, wave wv reduces row wv ----
  if (wv < 4) {
    float p = 0.f;
#pragma unroll
    for (int q = 0; q < DN / 64; ++q) {
      int d = lane + (q << 6);
      p += s_x[wv * SP + d] * W_tau[d];
    }
#pragma unroll
    for (int off = 32; off > 0; off >>= 1) p += __shfl_down(p, off);
    if (lane == 0) {
      float z = p + b_tau[0];
      float sp = z > 0.f ? z + log1pf(expf(-z)) : log1pf(expf(z));
      s_tau[wv] = fmaxf(sp, 0.01f) + 1.0f;
    }
  }
  __syncthreads();  // covers s_s and s_tau

  // ---- matvec passes: coalesced strip-dot, 4 chunks per wave ----
  auto ldchunk = [&](float4* g, const float* W, int hb) {
#pragma unroll
    for (int j = 0; j < 8; ++j)
      g[j] = *reinterpret_cast<const float4*>(W + ((size_t)(hb + j) << 8) +
                                              (lane << 2));
  };
  auto dotchunk = [&](const float4* w, const float4* sv) -> float {
    float v32[32];
#pragma unroll
    for (int j = 0; j < 8; ++j)
#pragma unroll
      for (int r = 0; r < 4; ++r) {
        float a = w[j].x * sv[r].x;
        a = fmaf(w[j].y, sv[r].y, a);
        a = fmaf(w[j].z, sv[r].z, a);
        a = fmaf(w[j].w, sv[r].w, a);
        v32[j * 4 + r] = a;
      }
    float v16[16], v8[8], v4[4], v2[2], vf;
#pragma unroll
    for (int m = 0; m < 16; ++m) {
      float keep = (lane & 1) ? v32[2 * m + 1] : v32[2 * m];
      float send = (lane & 1) ? v32[2 * m] : v32[2 * m + 1];
      v16[m] = keep + __shfl_xor(send, 1);
    }
#pragma unroll
    for (int m = 0; m < 8; ++m) {
      float keep = (lane & 2) ? v16[2 * m + 1] : v16[2 * m];
      float send = (lane & 2) ? v16[2 * m] : v16[2 * m + 1];
      v8[m] = keep + __shfl_xor(send, 2);
    }
#pragma unroll
    for (int m = 0; m < 4; ++m) {
      float keep = (lane & 4) ? v8[2 * m + 1] : v8[2 * m];
      float send = (lane & 4) ? v8[2 * m] : v8[2 * m + 1];
      v4[m] = keep + __shfl_xor(send, 4);
    }
#pragma unroll
    for (int m = 0; m < 2; ++m) {
      float keep = (lane & 8) ? v4[2 * m + 1] : v4[2 * m];
      float send = (lane & 8) ? v4[2 * m] : v4[2 * m + 1];
      v2[m] = keep + __shfl_xor(send, 8);
    }
    {
      float keep = (lane & 16) ? v2[1] : v2[0];
      float send = (lane & 16) ? v2[0] : v2[1];
      vf = keep + __shfl_xor(send, 16);
    }
    vf += __shfl_xor(vf, 32);
    return vf;
  };

  const int oj = (lane & 31) >> 2;
  const int orr = lane & 3;
  const int hbase = wv << 5;  // this wave's 32-h range

  // pass A: W_diff -> s_hk
  {
    float4 sA[4];
#pragma unroll
    for (int r = 0; r < 4; ++r)
      sA[r] = *reinterpret_cast<const float4*>(&s_s[r * SP + (lane << 2)]);
    float4 g[8];
    ldchunk(g, W_diff, hbase);
#pragma unroll
    for (int s = 0; s < 4; ++s) {
      float4 w[8];
#pragma unroll
      for (int j = 0; j < 8; ++j) w[j] = g[j];
      if (s < 3) ldchunk(g, W_diff, hbase + ((s + 1) << 3));
      float vf = dotchunk(w, sA);
      int h = hbase + (s << 3) + oj;
      s_hk[orr * SP + h] = (vf * 0.125f + b_diff[h]) / s_tau[orr];
    }
  }
  __syncthreads();

  // pass B: W_agg (on h_k) then W_res (on x); relu + residual -> s_y
  {
    float4 sH[4], sX[4];
#pragma unroll
    for (int r = 0; r < 4; ++r) {
      sH[r] = *reinterpret_cast<const float4*>(&s_hk[r * SP + (lane << 2)]);
      sX[r] = *reinterpret_cast<const float4*>(&s_x[r * SP + (lane << 2)]);
    }
    float aggv[4];
    float4 g[8];
    ldchunk(g, W_agg, hbase);
#pragma unroll
    for (int s = 0; s < 4; ++s) {
      float4 w[8];
#pragma unroll
      for (int j = 0; j < 8; ++j) w[j] = g[j];
      if (s < 3) ldchunk(g, W_agg, hbase + ((s + 1) << 3));
      aggv[s] = dotchunk(w, sH);
    }
    ldchunk(g, W_res, hbase);
#pragma unroll
    for (int s = 0; s < 4; ++s) {
      float4 w[8];
#pragma unroll
      for (int j = 0; j < 8; ++j) w[j] = g[j];
      if (s < 3) ldchunk(g, W_res, hbase + ((s + 1) << 3));
      float resv = dotchunk(w, sX);
      int h = hbase + (s << 3) + oj;
      float yv = fmaxf(aggv[s] + b_agg[h], 0.f) + resv + b_res[h];
      s_y[orr * SP + h] = yv;
    }
  }
  __syncthreads();

  // ---- LayerNorm: waves 0-3, wave wv reduces row wv ----
  if (wv < 4) {
    float sum = 0.f, sq = 0.f;
#pragma unroll
    for (int q = 0; q < HN / 64; ++q) {
      float v = s_y[wv * SP + lane + (q << 6)];
      sum += v;
      sq += v * v;
    }
#pragma unroll
    for (int off = 32; off > 0; off >>= 1) {
      sum += __shfl_down(sum, off);
      sq += __shfl_down(sq, off);
    }
    if (lane == 0) {
      float mu = sum * (1.f / HN);
      float var = sq * (1.f / HN) - mu * mu;
      s_mu[wv] = mu;
      s_rs[wv] = 1.f / sqrtf(var + 1e-5f);
    }
  }
  __syncthreads();

#pragma unroll
  for (int r2 = 0; r2 < 2; ++r2) {
    int rr = (half << 1) + r2;
    out[(size_t)(r0 + rr) * HN + t2] =
        (s_y[rr * SP + t2] - s_mu[rr]) * s_rs[rr] * gamma[t2] + beta[t2];
  }
}

extern "C" void kernel_launch(void* const* d_in, const int* in_sizes, int n_in,
                              void* d_out, int out_size, void* d_ws,
                              size_t ws_size, hipStream_t stream) {
  const float* x = (const float*)d_in[0];
  const float* W_diff = (const float*)d_in[1];
  const float* b_diff = (const float*)d_in[2];
  const float* W_tau = (const float*)d_in[3];
  const float* b_tau = (const float*)d_in[4];
  const float* W_agg = (const float*)d_in[5];
  const float* b_agg = (const float*)d_in[6];
  const float* W_res = (const float*)d_in[7];
  const float* b_res = (const float*)d_in[8];
  const float* gamma = (const float*)d_in[9];
  const float* beta = (const float*)d_in[10];
  float* out = (float*)d_out;

  float* dist2 = (float*)d_ws;  // 4 MB

  dim3 gA(BN / 64, BN / 64);
  k_dist2<<<gA, 512, 0, stream>>>(x, dist2);
  k_sel_row<<<BN / 4, 512, 0, stream>>>(x, W_diff, b_diff, W_tau, b_tau,
                                        W_agg, b_agg, W_res, b_res, gamma,
                                        beta, dist2, out);
}

// Round 11
// 109.906 us; speedup vs baseline: 1.1645x; 1.0069x over previous
//
#include <hip/hip_runtime.h>
#include <math.h>

#define BN 1024
#define DN 256
#define HN 256
#define KN 8
#define SP 260  // padded row stride (floats) for per-row LDS vectors
typedef unsigned long long u64;

// ---------------- Kernel A: pairwise squared distances ----------------
// UNCHANGED from R10 (validated: 512 thr = 2 waves/SIMD, bit-identical
// dist2). Near its LDS-BW/VALU floor (~7us model).
__global__ __launch_bounds__(512) void k_dist2(const float* __restrict__ x,
                                               float* __restrict__ dist2) {
  __shared__ float4 xi4[64][32];
  __shared__ float4 xj4[64][32];
  const int tid = threadIdx.x;
  const int tx = tid & 15, ty = tid >> 4;  // ty 0..31
  const int i0 = blockIdx.y << 6, j0 = blockIdx.x << 6;
  const int pim = (ty >> 1) & 7;
  const int pjm = tx & 7;
  float acc[2][4];
#pragma unroll
  for (int m = 0; m < 2; ++m)
#pragma unroll
    for (int n = 0; n < 4; ++n) acc[m][n] = 0.f;

  float4 A0[2], B0[4], A1[2], B1[4];

  auto loadg = [&](float4* Ad, float4* Bd, int g) {
    const int pi = g ^ pim, pj = g ^ pjm;
#pragma unroll
    for (int m = 0; m < 2; ++m) Ad[m] = xi4[(ty << 1) + m][pi];
#pragma unroll
    for (int n = 0; n < 4; ++n) Bd[n] = xj4[(tx << 2) + n][pj];
  };
  auto comp = [&](const float4* Ad, const float4* Bd) {
#pragma unroll
    for (int m = 0; m < 2; ++m)
#pragma unroll
      for (int n = 0; n < 4; ++n) {
        float t0 = Ad[m].x - Bd[n].x;
        float t1 = Ad[m].y - Bd[n].y;
        float t2 = Ad[m].z - Bd[n].z;
        float t3 = Ad[m].w - Bd[n].w;
        acc[m][n] = fmaf(t0, t0, acc[m][n]);
        acc[m][n] = fmaf(t1, t1, acc[m][n]);
        acc[m][n] = fmaf(t2, t2, acc[m][n]);
        acc[m][n] = fmaf(t3, t3, acc[m][n]);
      }
  };

  for (int c = 0; c < 2; ++c) {
    __syncthreads();
#pragma unroll
    for (int q = 0; q < 4; ++q) {
      int f = (q << 9) + tid;
      int row = f >> 5, s = f & 31;
      int p = s ^ ((row >> 2) & 7);
      xi4[row][p] = *reinterpret_cast<const float4*>(
          x + (size_t)(i0 + row) * DN + (c << 7) + (s << 2));
      xj4[row][p] = *reinterpret_cast<const float4*>(
          x + (size_t)(j0 + row) * DN + (c << 7) + (s << 2));
    }
    __syncthreads();

    loadg(A0, B0, 0);
    for (int g = 0; g < 32; g += 2) {
      loadg(A1, B1, g + 1);
      comp(A0, B0);
      loadg(A0, B0, (g + 2) & 31);
      comp(A1, B1);
    }
  }
#pragma unroll
  for (int m = 0; m < 2; ++m) {
    float4 o;
    o.x = acc[m][0]; o.y = acc[m][1]; o.z = acc[m][2]; o.w = acc[m][3];
    *reinterpret_cast<float4*>(dist2 + (size_t)(i0 + (ty << 1) + m) * BN +
                               j0 + (tx << 2)) = o;
  }
}

// ---------- Kernel B: fused top-K + epilogue, 16 waves (4/SIMD) ----------
// R10 structure at 1024 threads: wave w owns h in [16w,16w+16) (2 chunks
// of 8 per pass; dotchunk byte-identical -> bit-identical per-h results).
// Quarter q = tid>>8 owns row q for staging / |diff| / out. phase1 / tau /
// LN on waves 0-3 (short; other waves wait at the barrier they need anyway).
// 4 waves/SIMD doubles latency-hiding at the L2-resident W streams.
__global__ __launch_bounds__(1024) void k_sel_row(
    const float* __restrict__ x, const float* __restrict__ W_diff,
    const float* __restrict__ b_diff, const float* __restrict__ W_tau,
    const float* __restrict__ b_tau, const float* __restrict__ W_agg,
    const float* __restrict__ b_agg, const float* __restrict__ W_res,
    const float* __restrict__ b_res, const float* __restrict__ gamma,
    const float* __restrict__ beta, const float* __restrict__ dist2,
    float* __restrict__ out) {
  const int tid = threadIdx.x;
  const int lane = tid & 63, wv = tid >> 6;  // wv 0..15
  const int q4 = tid >> 8, t2 = tid & 255;   // quarter owns one row
  const int r0 = blockIdx.x << 2;
  __shared__ float s_x[4 * SP];
  __shared__ float s_s[4 * SP];
  __shared__ float s_hk[4 * SP];
  __shared__ float s_y[4 * SP];
  __shared__ float s_tau[4];
  __shared__ float s_mu[4], s_rs[4];
  __shared__ int s_idx[4 * KN];

  // stage x rows: quarter q4 stages row q4
  s_x[q4 * SP + t2] = x[(size_t)(r0 + q4) * DN + t2];

  // ---- phase 1: top-8 for row r0+wv on waves 0-3 (no barriers inside) ----
  if (wv < 4) {
    const int row = r0 + wv;
    const float* base = dist2 + (size_t)row * BN;
    u64 key[16];
#pragma unroll
    for (int q = 0; q < 4; ++q) {
      int j = (q << 8) + (lane << 2);
      float4 v = *reinterpret_cast<const float4*>(base + j);
      key[q * 4 + 0] = ((u64)__float_as_uint(v.x) << 32) | (unsigned)(j + 0);
      key[q * 4 + 1] = ((u64)__float_as_uint(v.y) << 32) | (unsigned)(j + 1);
      key[q * 4 + 2] = ((u64)__float_as_uint(v.z) << 32) | (unsigned)(j + 2);
      key[q * 4 + 3] = ((u64)__float_as_uint(v.w) << 32) | (unsigned)(j + 3);
    }
    for (int r = 0; r < KN; ++r) {
      u64 m = key[0];
#pragma unroll
      for (int l = 1; l < 16; ++l) m = key[l] < m ? key[l] : m;
#pragma unroll
      for (int off = 32; off > 0; off >>= 1) {
        u64 o = __shfl_xor(m, off);
        m = o < m ? o : m;
      }
      if (lane == 0) s_idx[wv * KN + r] = (int)(unsigned)(m & 0xffffffffull);
#pragma unroll
      for (int l = 0; l < 16; ++l)
        if (key[l] == m) key[l] = ~0ull;
    }
  }
  __syncthreads();  // s_idx + s_x visible

  // ---- |diff| sums over the K neighbors: quarter q4 does row q4 ----
  {
    float xv = s_x[q4 * SP + t2];
    float s = 0.f;
#pragma unroll
    for (int k = 0; k < KN; ++k) {
      int j = s_idx[q4 * KN + k];
      s += fabsf(xv - x[(size_t)j * DN + t2]);
    }
    s_s[q4 * SP + t2] = s;
  }
  // ---- tau: waves 0-3, wave wv reduces row wv ----
  if (wv < 4) {
    float p = 0.f;
#pragma unroll
    for (int q = 0; q < DN / 64; ++q) {
      int d = lane + (q << 6);
      p += s_x[wv * SP + d] * W_tau[d];
    }
#pragma unroll
    for (int off = 32; off > 0; off >>= 1) p += __shfl_down(p, off);
    if (lane == 0) {
      float z = p + b_tau[0];
      float sp = z > 0.f ? z + log1pf(expf(-z)) : log1pf(expf(z));
      s_tau[wv] = fmaxf(sp, 0.01f) + 1.0f;
    }
  }
  __syncthreads();  // covers s_s and s_tau

  // ---- matvec passes: coalesced strip-dot, 2 chunks per wave ----
  auto ldchunk = [&](float4* g, const float* W, int hb) {
#pragma unroll
    for (int j = 0; j < 8; ++j)
      g[j] = *reinterpret_cast<const float4*>(W + ((size_t)(hb + j) << 8) +
                                              (lane << 2));
  };
  auto dotchunk = [&](const float4* w, const float4* sv) -> float {
    float v32[32];
#pragma unroll
    for (int j = 0; j < 8; ++j)
#pragma unroll
      for (int r = 0; r < 4; ++r) {
        float a = w[j].x * sv[r].x;
        a = fmaf(w[j].y, sv[r].y, a);
        a = fmaf(w[j].z, sv[r].z, a);
        a = fmaf(w[j].w, sv[r].w, a);
        v32[j * 4 + r] = a;
      }
    float v16[16], v8[8], v4[4], v2[2], vf;
#pragma unroll
    for (int m = 0; m < 16; ++m) {
      float keep = (lane & 1) ? v32[2 * m + 1] : v32[2 * m];
      float send = (lane & 1) ? v32[2 * m] : v32[2 * m + 1];
      v16[m] = keep + __shfl_xor(send, 1);
    }
#pragma unroll
    for (int m = 0; m < 8; ++m) {
      float keep = (lane & 2) ? v16[2 * m + 1] : v16[2 * m];
      float send = (lane & 2) ? v16[2 * m] : v16[2 * m + 1];
      v8[m] = keep + __shfl_xor(send, 2);
    }
#pragma unroll
    for (int m = 0; m < 4; ++m) {
      float keep = (lane & 4) ? v8[2 * m + 1] : v8[2 * m];
      float send = (lane & 4) ? v8[2 * m] : v8[2 * m + 1];
      v4[m] = keep + __shfl_xor(send, 4);
    }
#pragma unroll
    for (int m = 0; m < 2; ++m) {
      float keep = (lane & 8) ? v4[2 * m + 1] : v4[2 * m];
      float send = (lane & 8) ? v4[2 * m] : v4[2 * m + 1];
      v2[m] = keep + __shfl_xor(send, 8);
    }
    {
      float keep = (lane & 16) ? v2[1] : v2[0];
      float send = (lane & 16) ? v2[0] : v2[1];
      vf = keep + __shfl_xor(send, 16);
    }
    vf += __shfl_xor(vf, 32);
    return vf;
  };

  const int oj = (lane & 31) >> 2;
  const int orr = lane & 3;
  const int hbase = wv << 4;  // this wave's 16-h range

  // pass A: W_diff -> s_hk
  {
    float4 sA[4];
#pragma unroll
    for (int r = 0; r < 4; ++r)
      sA[r] = *reinterpret_cast<const float4*>(&s_s[r * SP + (lane << 2)]);
    float4 g[8];
    ldchunk(g, W_diff, hbase);
#pragma unroll
    for (int s = 0; s < 2; ++s) {
      float4 w[8];
#pragma unroll
      for (int j = 0; j < 8; ++j) w[j] = g[j];
      if (s < 1) ldchunk(g, W_diff, hbase + 8);
      float vf = dotchunk(w, sA);
      int h = hbase + (s << 3) + oj;
      s_hk[orr * SP + h] = (vf * 0.125f + b_diff[h]) / s_tau[orr];
    }
  }
  __syncthreads();

  // pass B: W_agg (on h_k) then W_res (on x); relu + residual -> s_y
  {
    float4 sH[4], sX[4];
#pragma unroll
    for (int r = 0; r < 4; ++r) {
      sH[r] = *reinterpret_cast<const float4*>(&s_hk[r * SP + (lane << 2)]);
      sX[r] = *reinterpret_cast<const float4*>(&s_x[r * SP + (lane << 2)]);
    }
    float aggv[2];
    float4 g[8];
    ldchunk(g, W_agg, hbase);
#pragma unroll
    for (int s = 0; s < 2; ++s) {
      float4 w[8];
#pragma unroll
      for (int j = 0; j < 8; ++j) w[j] = g[j];
      if (s < 1) ldchunk(g, W_agg, hbase + 8);
      aggv[s] = dotchunk(w, sH);
    }
    ldchunk(g, W_res, hbase);
#pragma unroll
    for (int s = 0; s < 2; ++s) {
      float4 w[8];
#pragma unroll
      for (int j = 0; j < 8; ++j) w[j] = g[j];
      if (s < 1) ldchunk(g, W_res, hbase + 8);
      float resv = dotchunk(w, sX);
      int h = hbase + (s << 3) + oj;
      float yv = fmaxf(aggv[s] + b_agg[h], 0.f) + resv + b_res[h];
      s_y[orr * SP + h] = yv;
    }
  }
  __syncthreads();

  // ---- LayerNorm: waves 0-3, wave wv reduces row wv ----
  if (wv < 4) {
    float sum = 0.f, sq = 0.f;
#pragma unroll
    for (int q = 0; q < HN / 64; ++q) {
      float v = s_y[wv * SP + lane + (q << 6)];
      sum += v;
      sq += v * v;
    }
#pragma unroll
    for (int off = 32; off > 0; off >>= 1) {
      sum += __shfl_down(sum, off);
      sq += __shfl_down(sq, off);
    }
    if (lane == 0) {
      float mu = sum * (1.f / HN);
      float var = sq * (1.f / HN) - mu * mu;
      s_mu[wv] = mu;
      s_rs[wv] = 1.f / sqrtf(var + 1e-5f);
    }
  }
  __syncthreads();

  out[(size_t)(r0 + q4) * HN + t2] =
      (s_y[q4 * SP + t2] - s_mu[q4]) * s_rs[q4] * gamma[t2] + beta[t2];
}

extern "C" void kernel_launch(void* const* d_in, const int* in_sizes, int n_in,
                              void* d_out, int out_size, void* d_ws,
                              size_t ws_size, hipStream_t stream) {
  const float* x = (const float*)d_in[0];
  const float* W_diff = (const float*)d_in[1];
  const float* b_diff = (const float*)d_in[2];
  const float* W_tau = (const float*)d_in[3];
  const float* b_tau = (const float*)d_in[4];
  const float* W_agg = (const float*)d_in[5];
  const float* b_agg = (const float*)d_in[6];
  const float* W_res = (const float*)d_in[7];
  const float* b_res = (const float*)d_in[8];
  const float* gamma = (const float*)d_in[9];
  const float* beta = (const float*)d_in[10];
  float* out = (float*)d_out;

  float* dist2 = (float*)d_ws;  // 4 MB

  dim3 gA(BN / 64, BN / 64);
  k_dist2<<<gA, 512, 0, stream>>>(x, dist2);
  k_sel_row<<<BN / 4, 1024, 0, stream>>>(x, W_diff, b_diff, W_tau, b_tau,
                                         W_agg, b_agg, W_res, b_res, gamma,
                                         beta, dist2, out);
}